// Round 8
// baseline (2217.706 us; speedup 1.0000x reference)
//
#include <hip/hip_runtime.h>
#include <hip/hip_bf16.h>
#include <stdint.h>

#define NB 400
#define NC 151
#define DX 4096
#define DE 200
#define DP 128
#define DH 512
#define KREP 4424   // 4096 + 200 + 128
#define TAILW 328   // DE + DP
#define MPAD 416    // 13*32 rows, padded
#define SPLITK 8
#define TILES1 139  // ceil(4424/32) - GEMM1 full K
#define TILES2 132  // 4224/32     - GEMM2a label-independent K
#define NGB 832     // gemm blocks per phase: 8 n * 13 m * 8 z
#define NBINS 65536
#define NKEYS 60000 // 400 rows * 150 cols

__device__ __forceinline__ uint32_t f2ord(float f) {
  uint32_t u = __float_as_uint(f);
  return (u & 0x80000000u) ? ~u : (u | 0x80000000u);
}

// ---------------------------------------------------------------------------
// k_embed: softmax(logits) @ obj_embed_w and pos path -> packed tail1 =
// [obj_embed(200) | pos_embed(128)]. Rows 400..415 zero. Also zeroes hist.
// ---------------------------------------------------------------------------
__global__ __launch_bounds__(256) void k_embed(
    const float* __restrict__ logits, const float* __restrict__ obj_embed_w,
    const float* __restrict__ pos_input, const float* __restrict__ w_pos1,
    const float* __restrict__ b_pos1, const float* __restrict__ bn_gamma,
    const float* __restrict__ bn_beta, const float* __restrict__ bn_mean,
    const float* __restrict__ bn_var, const float* __restrict__ w_pos2,
    const float* __restrict__ b_pos2, float* __restrict__ tail1,
    uint32_t* __restrict__ hist) {
  int r = blockIdx.x, t = threadIdx.x;
  int gid = r * 256 + t;
  if (gid < NBINS) hist[gid] = 0;
  if (r >= NB) {
    if (t < TAILW) tail1[r * TAILW + t] = 0.f;
    return;
  }
  __shared__ float p[NC];
  __shared__ float red[256];
  __shared__ float hb[32];

  float v = (t < NC) ? logits[r * NC + t] : -INFINITY;
  red[t] = v; __syncthreads();
  for (int s = 128; s > 0; s >>= 1) { if (t < s) red[t] = fmaxf(red[t], red[t + s]); __syncthreads(); }
  float m = red[0]; __syncthreads();
  float e = (t < NC) ? expf(v - m) : 0.f;
  red[t] = e; __syncthreads();
  for (int s = 128; s > 0; s >>= 1) { if (t < s) red[t] += red[t + s]; __syncthreads(); }
  float sum = red[0];
  if (t < NC) p[t] = e / sum;

  if (t < 32) {
    float acc = b_pos1[t];
    for (int k = 0; k < 9; k++) acc += pos_input[r * 9 + k] * w_pos1[k * 32 + t];
    acc = (acc - bn_mean[t]) / sqrtf(bn_var[t] + 1e-5f) * bn_gamma[t] + bn_beta[t];
    hb[t] = acc;
  }
  __syncthreads();

  if (t < DE) {
    float acc = 0.f;
    for (int k = 0; k < NC; k++) acc += p[k] * obj_embed_w[k * DE + t];
    tail1[r * TAILW + t] = acc;
  }
  if (t < DP) {
    float acc = b_pos2[t];
    for (int k = 0; k < 32; k++) acc += hb[k] * w_pos2[k * DP + t];
    tail1[r * TAILW + DE + t] = fmaxf(acc, 0.f);
  }
}

// ---------------------------------------------------------------------------
// gemm_body: split-K partial GEMM tile, 32(M)x64(N), BK=32, 2x4 microtile,
// register prefetch (round-6 shape). toff: 0 = full tail1; DE = pos segment.
// ---------------------------------------------------------------------------
__device__ __forceinline__ void gemm_body(
    const float* __restrict__ x, const float* __restrict__ tail,
    const float* __restrict__ w, float* __restrict__ part,
    int bid, int tiles, int toff, float* As, float* Bs) {
  int tid = threadIdx.x;
  int n0 = (bid & 7) * 64, m0 = ((bid >> 3) % 13) * 32;
  int z = bid / 104;
  int tbeg = (z * tiles) / SPLITK, tend = ((z + 1) * tiles) / SPLITK;
  int ty = tid >> 4, tx = tid & 15;
  int a_r = tid >> 3, a_c = (tid & 7) << 2;
  int b_r = tid >> 4, b_c = (tid & 15) << 2;
  float4 acc0 = {0, 0, 0, 0}, acc1 = {0, 0, 0, 0};

  auto loadA = [&](int t) -> float4 {
    int k = t * 32 + a_c;
    int row = m0 + a_r;
    float4 v = {0, 0, 0, 0};
    if (k < KREP) {
      if (k < DX) { if (row < NB) v = *(const float4*)&x[(size_t)row * DX + k]; }
      else v = *(const float4*)&tail[row * TAILW + toff + (k - DX)];
    }
    return v;
  };
  auto loadB = [&](int t, int roff) -> float4 {
    int k = t * 32 + b_r + roff;
    float4 v = {0, 0, 0, 0};
    if (k < KREP) v = *(const float4*)&w[(size_t)k * DH + n0 + b_c];
    return v;
  };

  float4 pa = loadA(tbeg), pb0 = loadB(tbeg, 0), pb1 = loadB(tbeg, 16);
  for (int t = tbeg; t < tend; t++) {
    __syncthreads();
    *(float4*)&As[a_r * 36 + a_c] = pa;
    *(float4*)&Bs[b_r * 68 + b_c] = pb0;
    *(float4*)&Bs[(b_r + 16) * 68 + b_c] = pb1;
    __syncthreads();
    if (t + 1 < tend) { pa = loadA(t + 1); pb0 = loadB(t + 1, 0); pb1 = loadB(t + 1, 16); }
#pragma unroll
    for (int k4 = 0; k4 < 8; k4++) {
      float4 a0 = *(float4*)&As[(ty * 2) * 36 + k4 * 4];
      float4 a1 = *(float4*)&As[(ty * 2 + 1) * 36 + k4 * 4];
#pragma unroll
      for (int j = 0; j < 4; j++) {
        float4 bv = *(float4*)&Bs[(k4 * 4 + j) * 68 + tx * 4];
        float av0 = (&a0.x)[j], av1 = (&a1.x)[j];
        acc0.x += av0 * bv.x; acc0.y += av0 * bv.y; acc0.z += av0 * bv.z; acc0.w += av0 * bv.w;
        acc1.x += av1 * bv.x; acc1.y += av1 * bv.y; acc1.z += av1 * bv.z; acc1.w += av1 * bv.w;
      }
    }
  }
  int row0 = m0 + ty * 2, col = n0 + tx * 4;
  float* base = part + (size_t)z * NB * DH;
  if (row0 < NB)     *(float4*)&base[row0 * DH + col] = acc0;
  if (row0 + 1 < NB) *(float4*)&base[(row0 + 1) * DH + col] = acc1;
}

// ---------------------------------------------------------------------------
// k_g1ov: blocks 0..831 = GEMM1 partials; blocks 832..982 = IoU bit matrix.
// ---------------------------------------------------------------------------
__global__ __launch_bounds__(256) void k_g1ov(
    const float* __restrict__ x, const float* __restrict__ tail1,
    const float* __restrict__ w_lin, float* __restrict__ part,
    const float* __restrict__ boxes, uint64_t* __restrict__ ov_bits) {
  __shared__ __align__(16) char pool[13312];
  int bid = blockIdx.x;
  if (bid >= NGB) {
    int c = bid - NGB;
    int t = threadIdx.x;
    float4* bx = (float4*)pool;
    const float4* bp4 = (const float4*)boxes;
    for (int j = t; j < NB; j += 256) bx[j] = bp4[j * NC + c];
    __syncthreads();
    int wave = t >> 6, lane = t & 63;
    for (int b = wave; b < NB; b += 4) {
      float4 A = bx[b];
      float areaA = (A.z - A.x + 1.f) * (A.w - A.y + 1.f);
      for (int chunk = 0; chunk < 7; chunk++) {
        int j = chunk * 64 + lane;
        bool ov = false;
        if (j < NB) {
          float4 B = bx[j];
          float x1 = fmaxf(A.x, B.x), y1 = fmaxf(A.y, B.y);
          float x2 = fminf(A.z, B.z), y2 = fminf(A.w, B.w);
          float iw = fmaxf(x2 - x1 + 1.f, 0.f), ih = fmaxf(y2 - y1 + 1.f, 0.f);
          float inter = iw * ih;
          float areaB = (B.z - B.x + 1.f) * (B.w - B.y + 1.f);
          ov = (inter / (areaA + areaB - inter)) >= 0.5f;
        }
        uint64_t mask = __ballot(ov);
        if (lane == 0) ov_bits[((size_t)(b * NC + c) << 3) + chunk] = mask;
      }
    }
    return;
  }
  gemm_body(x, tail1, w_lin, part, bid, TILES1, 0,
            (float*)pool, (float*)(pool + 4608));
}

// ---------------------------------------------------------------------------
// k_dists: hidden = sum of GEMM1 partials + b_lin (LDS); obj_dists -> d_out;
// softmax; emit UNSORTED keys + 16-bit-bin histogram (counting sort prep).
// key = (f2ord(v)<<17) | ((511-r)<<8) | col ; bin = 65535 - (key>>33).
// ---------------------------------------------------------------------------
__global__ __launch_bounds__(256) void k_dists(
    const float* __restrict__ part, const float* __restrict__ b_lin,
    const float* __restrict__ w_out, const float* __restrict__ b_out,
    float* __restrict__ out_dists, uint64_t* __restrict__ ukeys,
    uint32_t* __restrict__ hist) {
  int r = blockIdx.x, t = threadIdx.x;
  __shared__ float h[DH];
  __shared__ float red[256];
  float s0 = b_lin[t], s1 = b_lin[t + 256];
#pragma unroll
  for (int z = 0; z < SPLITK; z++) {
    const float* pr = part + ((size_t)z * NB + r) * DH;
    s0 += pr[t]; s1 += pr[t + 256];
  }
  h[t] = s0; h[t + 256] = s1;
  __syncthreads();

  float acc = -INFINITY;
  if (t < NC) {
    acc = b_out[t];
    for (int k = 0; k < DH; k++) acc += h[k] * w_out[k * NC + t];
    out_dists[r * NC + t] = acc;
  }
  red[t] = (t < NC) ? acc : -INFINITY; __syncthreads();
  for (int s = 128; s > 0; s >>= 1) { if (t < s) red[t] = fmaxf(red[t], red[t + s]); __syncthreads(); }
  float mx = red[0]; __syncthreads();
  float e = (t < NC) ? expf(acc - mx) : 0.f;
  red[t] = e; __syncthreads();
  for (int s = 128; s > 0; s >>= 1) { if (t < s) red[t] += red[t + s]; __syncthreads(); }
  float sum = red[0];

  if (t >= 1 && t < NC) {
    float v = e / sum;
    uint64_t key = ((uint64_t)f2ord(v) << 17) | ((uint64_t)(511 - r) << 8) | (uint64_t)t;
    ukeys[r * 150 + (t - 1)] = key;
    atomicAdd(&hist[NBINS - 1 - (uint32_t)(key >> 33)], 1u);
  }
}

// ---------------------------------------------------------------------------
// k_sps: exclusive prefix-sum of 65536-bin histogram -> bases & cursor.
// ---------------------------------------------------------------------------
__global__ __launch_bounds__(1024) void k_sps(
    const uint32_t* __restrict__ hist, uint32_t* __restrict__ bases,
    uint32_t* __restrict__ cursor) {
  __shared__ uint32_t tsum[1024];
  int t = threadIdx.x;
  uint32_t s = 0;
  for (int i = 0; i < 64; i++) s += hist[t * 64 + i];
  tsum[t] = s;
  __syncthreads();
  for (int off = 1; off < 1024; off <<= 1) {
    uint32_t v = (t >= off) ? tsum[t - off] : 0;
    __syncthreads();
    tsum[t] += v;
    __syncthreads();
  }
  uint32_t run = tsum[t] - s;   // exclusive base of this thread's chunk
  for (int i = 0; i < 64; i++) {
    uint32_t hh = hist[t * 64 + i];
    bases[t * 64 + i] = run;
    cursor[t * 64 + i] = run;
    run += hh;
  }
  if (t == 1023) bases[NBINS] = run;
}

// ---------------------------------------------------------------------------
// k_scatter: keys -> bin ranges (order within bin arbitrary; sorted next).
// ---------------------------------------------------------------------------
__global__ __launch_bounds__(256) void k_scatter(
    const uint64_t* __restrict__ ukeys, uint32_t* __restrict__ cursor,
    uint64_t* __restrict__ gkeys) {
  int i = blockIdx.x * 256 + threadIdx.x;
  if (i < NKEYS) {
    uint64_t key = ukeys[i];
    uint32_t bin = NBINS - 1 - (uint32_t)(key >> 33);
    uint32_t pos = atomicAdd(&cursor[bin], 1u);
    gkeys[pos] = key;
  } else if (i < NKEYS + 64) {
    gkeys[i] = 0;   // pad for the walk's last batch
  }
}

// ---------------------------------------------------------------------------
// k_binsort: sort each bin descending (bitonic in LDS; serial fallback).
// 256 blocks x 256 bins each.
// ---------------------------------------------------------------------------
__global__ __launch_bounds__(256) void k_binsort(
    const uint32_t* __restrict__ bases, uint64_t* __restrict__ gkeys) {
  __shared__ uint64_t buf[1024];
  __shared__ uint32_t bbase[257];
  int tid = threadIdx.x;
  int b0 = blockIdx.x * 256;
  for (int i = tid; i < 257; i += 256) bbase[i] = bases[b0 + i];
  __syncthreads();
  for (int bi = 0; bi < 256; bi++) {
    int lo = (int)bbase[bi], n = (int)bbase[bi + 1] - lo;
    if (n < 2) continue;
    if (n <= 1024) {
      int p2 = 1; while (p2 < n) p2 <<= 1;
      for (int i = tid; i < p2; i += 256) buf[i] = (i < n) ? gkeys[lo + i] : 0;
      __syncthreads();
      for (int k = 2; k <= p2; k <<= 1) {
        for (int j = k >> 1; j > 0; j >>= 1) {
          for (int i = tid; i < p2; i += 256) {
            int ix = i ^ j;
            if (ix > i) {
              uint64_t av = buf[i], bv = buf[ix];
              bool desc = ((i & k) == 0);
              if (desc ? (av < bv) : (av > bv)) { buf[i] = bv; buf[ix] = av; }
            }
          }
          __syncthreads();
        }
      }
      for (int i = tid; i < n; i += 256) gkeys[lo + i] = buf[i];
      __syncthreads();
    } else {
      if (tid == 0) {   // pathological fallback: serial insertion, descending
        for (int a = 1; a < n; a++) {
          uint64_t k = gkeys[lo + a];
          int b = a - 1;
          while (b >= 0 && gkeys[lo + b] < k) { gkeys[lo + b + 1] = gkeys[lo + b]; b--; }
          gkeys[lo + b + 1] = k;
        }
      }
      __syncthreads();
    }
  }
}

// ---------------------------------------------------------------------------
// k_nms_g2a: block 0 = sorted-walk greedy NMS (single wave, no butterfly);
// blocks 1..832 = GEMM2a partials over K in [0,4224), hidden under NMS.
// Walk: visit entries in global (value desc, row asc, col asc) order; pick
// iff row alive && not suppressed; first-valid == current global argmax.
// Zero phase (rare): exact flat-min over resurrection/fully-suppressed rows.
// ---------------------------------------------------------------------------
__global__ __launch_bounds__(256) void k_nms_g2a(
    const uint64_t* __restrict__ ov_bits, const uint64_t* __restrict__ gkeys,
    int* __restrict__ labels_g, float* __restrict__ out_preds,
    const float* __restrict__ x, const float* __restrict__ tail1,
    const float* __restrict__ w_fc, float* __restrict__ part) {
  __shared__ __align__(16) char pool[13312];
  if (blockIdx.x > 0) {
    gemm_body(x, tail1, w_fc, part, blockIdx.x - 1, TILES2, DE,
              (float*)pool, (float*)(pool + 4608));
    return;
  }
  uint64_t* suppL = (uint64_t*)pool;            // 448*3 u64 = 10752 B
  uint32_t* reszL = (uint32_t*)(pool + 10752);  // 448 u32 = 1792 B
  int tid = threadIdx.x;
  if (tid >= 64) return;
  int lane = tid;
  for (int i = lane; i < 448 * 3; i += 64) suppL[i] = 0;
  for (int i = lane; i < 448; i += 64) reszL[i] = 255u;
  for (int r = lane; r < NB; r += 64) { labels_g[r] = 0; out_preds[r] = 0.f; }
  uint64_t rem[7] = {0, 0, 0, 0, 0, 0, 0};

  int picked = 0, pos = 0;
  while (picked < NB && pos < NKEYS) {
    int i = pos + lane;
    uint64_t key = gkeys[i];                    // padded with 0 past NKEYS
    bool hask = (key != 0) && (i < NKEYS);
    int r = hask ? (511 - (int)((key >> 8) & 0x1FF)) : 0;
    int c = hask ? (int)(key & 0xFF) : 0;
    // concurrent prefetch of this entry's overlap row (7 u64)
    const uint64_t* prow = ov_bits + (((size_t)(r * NC + c)) << 3);
    uint64_t pf[7];
#pragma unroll
    for (int k = 0; k < 7; k++) pf[k] = prow[k];
    bool valid = hask;
    if (valid) {
      uint64_t rb = 0;
#pragma unroll
      for (int s = 0; s < 7; s++) if (s == (r >> 6)) rb = rem[s];
      valid = !((rb >> (r & 63)) & 1);
    }
    if (valid) {
      uint64_t sb = suppL[r * 3 + (c >> 6)];
      valid = !((sb >> (c & 63)) & 1);
    }
    uint64_t live = __ballot(valid);
    while (live != 0 && picked < NB) {
      int p = __ffsll((unsigned long long)live) - 1;
      uint64_t kp = (uint64_t)__shfl((unsigned long long)key, p, 64);
      int rp = 511 - (int)((kp >> 8) & 0x1FF);
      int cp = (int)(kp & 0xFF);
      uint64_t ow[7];
#pragma unroll
      for (int k = 0; k < 7; k++)
        ow[k] = (uint64_t)__shfl((unsigned long long)pf[k], p, 64);
      if (lane == p) { labels_g[rp] = cp; out_preds[rp] = (float)cp; }
#pragma unroll
      for (int s = 0; s < 7; s++) if (s == (rp >> 6)) rem[s] |= (1ull << (rp & 63));
      // suppression / resurrection-min updates for my rows
#pragma unroll
      for (int s = 0; s < 7; s++) {
        if ((ow[s] >> lane) & 1) {
          int rr = s * 64 + lane;
          if (rr != rp && rr < NB) {
            if ((rem[s] >> lane) & 1) {
              if ((uint32_t)cp < reszL[rr]) reszL[rr] = (uint32_t)cp;
            } else {
              suppL[rr * 3 + (cp >> 6)] |= (1ull << (cp & 63));
            }
          }
        }
      }
      // in-batch invalidation
      if (valid) {
        if (r == rp) valid = false;
        else if (c == cp) {
          uint64_t w2 = 0;
#pragma unroll
          for (int s = 0; s < 7; s++) if (s == (r >> 6)) w2 = ow[s];
          if ((w2 >> (r & 63)) & 1) valid = false;
        }
      }
      if (lane == p) valid = false;
      picked++;
      live = __ballot(valid);
    }
    pos += 64;
  }

  // zero phase (rare): remaining picks have current value 0.0, flat order.
  while (picked < NB) {
    uint32_t best = 0xFFFFFFFFu;
#pragma unroll
    for (int s = 0; s < 7; s++) {
      int r = s * 64 + lane;
      if (r < NB) {
        uint32_t cand = 0xFFFFFFFFu;
        if ((rem[s] >> lane) & 1) {
          uint32_t z = reszL[r];
          if (z < 255u) cand = (uint32_t)(r * NC) + z;
        } else {
          int pc = __popcll(suppL[r * 3]) + __popcll(suppL[r * 3 + 1]) +
                   __popcll(suppL[r * 3 + 2]);
          if (pc >= 150) cand = (uint32_t)(r * NC) + 1u;
        }
        if (cand < best) best = cand;
      }
    }
    for (int off = 1; off < 64; off <<= 1) {
      uint32_t o = (uint32_t)__shfl_xor((int)best, off, 64);
      if (o < best) best = o;
    }
    if (best == 0xFFFFFFFFu) break;  // degenerate cascade: labels all default
    int rp = (int)(best / NC), cp = (int)(best % NC);
    uint64_t wv = (lane < 7) ? ov_bits[(((size_t)(rp * NC + cp)) << 3) + lane] : 0;
    uint64_t ow[7];
#pragma unroll
    for (int k = 0; k < 7; k++) ow[k] = (uint64_t)__shfl((unsigned long long)wv, k, 64);
    if (lane == 0) { labels_g[rp] = cp; out_preds[rp] = (float)cp; reszL[rp] = 255u; }
#pragma unroll
    for (int s = 0; s < 7; s++) if (s == (rp >> 6)) rem[s] |= (1ull << (rp & 63));
#pragma unroll
    for (int s = 0; s < 7; s++) {
      if ((ow[s] >> lane) & 1) {
        int rr = s * 64 + lane;
        if (rr != rp && rr < NB) {
          if ((rem[s] >> lane) & 1) {
            if ((uint32_t)cp < reszL[rr]) reszL[rr] = (uint32_t)cp;
          } else {
            suppL[rr * 3 + (cp >> 6)] |= (1ull << (cp & 63));
          }
        }
      }
    }
    picked++;
  }
}

// ---------------------------------------------------------------------------
// k_final: edge_ctx = relu( GEMM2a-partials + emb2[labels] @ w_fc[4224:] + b_fc )
// ---------------------------------------------------------------------------
__global__ __launch_bounds__(256) void k_final(
    const float* __restrict__ emb2, const int* __restrict__ labels,
    const float* __restrict__ w_fc, const float* __restrict__ part,
    const float* __restrict__ b_fc, float* __restrict__ out_edge) {
  __shared__ __align__(16) float As[32][36];
  __shared__ __align__(16) float Bs[32][68];
  int tid = threadIdx.x;
  int n0 = blockIdx.x * 64, m0 = blockIdx.y * 32;
  int ty = tid >> 4, tx = tid & 15;
  int a_r = tid >> 3, a_c = (tid & 7) << 2;
  int b_r = tid >> 4, b_c = (tid & 15) << 2;
  float4 acc0 = {0, 0, 0, 0}, acc1 = {0, 0, 0, 0};
  int row_a = m0 + a_r;
  int lab = (row_a < NB) ? labels[row_a] : 0;

  auto loadA = [&](int t) -> float4 {
    int kk = t * 32 + a_c;
    float4 v = {0, 0, 0, 0};
    if (kk < DE && row_a < NB) v = *(const float4*)&emb2[(size_t)lab * DE + kk];
    return v;
  };
  auto loadB = [&](int t, int roff) -> float4 {
    int kk = t * 32 + b_r + roff;
    float4 v = {0, 0, 0, 0};
    if (kk < DE) v = *(const float4*)&w_fc[(size_t)(DX + DP + kk) * DH + n0 + b_c];
    return v;
  };

  float4 pa = loadA(0), pb0 = loadB(0, 0), pb1 = loadB(0, 16);
  for (int t = 0; t < 7; t++) {
    __syncthreads();
    *(float4*)&As[a_r][a_c] = pa;
    *(float4*)&Bs[b_r][b_c] = pb0;
    *(float4*)&Bs[b_r + 16][b_c] = pb1;
    __syncthreads();
    if (t + 1 < 7) { pa = loadA(t + 1); pb0 = loadB(t + 1, 0); pb1 = loadB(t + 1, 16); }
#pragma unroll
    for (int k4 = 0; k4 < 8; k4++) {
      float4 a0 = *(float4*)&As[ty * 2][k4 * 4];
      float4 a1 = *(float4*)&As[ty * 2 + 1][k4 * 4];
#pragma unroll
      for (int j = 0; j < 4; j++) {
        float4 bv = *(float4*)&Bs[k4 * 4 + j][tx * 4];
        float av0 = (&a0.x)[j], av1 = (&a1.x)[j];
        acc0.x += av0 * bv.x; acc0.y += av0 * bv.y; acc0.z += av0 * bv.z; acc0.w += av0 * bv.w;
        acc1.x += av1 * bv.x; acc1.y += av1 * bv.y; acc1.z += av1 * bv.z; acc1.w += av1 * bv.w;
      }
    }
  }
  int row0 = m0 + ty * 2, col = n0 + tx * 4;
#pragma unroll
  for (int z = 0; z < SPLITK; z++) {
    if (row0 < NB) {
      float4 p = *(const float4*)&part[((size_t)z * NB + row0) * DH + col];
      acc0.x += p.x; acc0.y += p.y; acc0.z += p.z; acc0.w += p.w;
    }
    if (row0 + 1 < NB) {
      float4 p = *(const float4*)&part[((size_t)z * NB + row0 + 1) * DH + col];
      acc1.x += p.x; acc1.y += p.y; acc1.z += p.z; acc1.w += p.w;
    }
  }
  float4 bv = *(const float4*)&b_fc[col];
  if (row0 < NB) {
    float4 r;
    r.x = fmaxf(acc0.x + bv.x, 0.f); r.y = fmaxf(acc0.y + bv.y, 0.f);
    r.z = fmaxf(acc0.z + bv.z, 0.f); r.w = fmaxf(acc0.w + bv.w, 0.f);
    *(float4*)&out_edge[row0 * DH + col] = r;
  }
  if (row0 + 1 < NB) {
    float4 r;
    r.x = fmaxf(acc1.x + bv.x, 0.f); r.y = fmaxf(acc1.y + bv.y, 0.f);
    r.z = fmaxf(acc1.z + bv.z, 0.f); r.w = fmaxf(acc1.w + bv.w, 0.f);
    *(float4*)&out_edge[(row0 + 1) * DH + col] = r;
  }
}

// ---------------------------------------------------------------------------
extern "C" void kernel_launch(void* const* d_in, const int* in_sizes, int n_in,
                              void* d_out, int out_size, void* d_ws, size_t ws_size,
                              hipStream_t stream) {
  const float* x            = (const float*)d_in[0];
  const float* logits       = (const float*)d_in[1];
  const float* pos_input    = (const float*)d_in[2];
  const float* boxes        = (const float*)d_in[3];
  const float* obj_embed_w  = (const float*)d_in[4];
  const float* obj_embed2_w = (const float*)d_in[5];
  const float* w_pos1       = (const float*)d_in[6];
  const float* b_pos1       = (const float*)d_in[7];
  const float* bn_gamma     = (const float*)d_in[8];
  const float* bn_beta      = (const float*)d_in[9];
  const float* bn_mean      = (const float*)d_in[10];
  const float* bn_var       = (const float*)d_in[11];
  const float* w_pos2       = (const float*)d_in[12];
  const float* b_pos2       = (const float*)d_in[13];
  const float* w_lin        = (const float*)d_in[14];
  const float* b_lin        = (const float*)d_in[15];
  const float* w_out        = (const float*)d_in[16];
  const float* b_out        = (const float*)d_in[17];
  const float* w_fc         = (const float*)d_in[18];
  const float* b_fc         = (const float*)d_in[19];

  char* wp = (char*)d_ws;
  float* tail1      = (float*)wp;  wp += (size_t)MPAD * TAILW * 4;   // 545792
  int* labels       = (int*)wp;    wp += 512 * 4;                    // 2048
  uint32_t* hist    = (uint32_t*)wp; wp += (size_t)NBINS * 4;        // 262144
  uint32_t* bases   = (uint32_t*)wp; wp += (size_t)(NBINS + 4) * 4;  // 262160
  uint32_t* cursor  = (uint32_t*)wp; wp += (size_t)NBINS * 4;        // 262144
  uint64_t* ukeys   = (uint64_t*)wp; wp += (size_t)60032 * 8;        // 480256
  uint64_t* gkeys   = (uint64_t*)wp; wp += (size_t)60032 * 8;
  uint64_t* ov_bits = (uint64_t*)wp; wp += (size_t)NB * NC * 8 * 8;  // 3.87 MB
  float* part       = (float*)wp;                                    // 6.55 MB

  float* out       = (float*)d_out;
  float* out_dists = out;                 // 400*151
  float* out_preds = out + NB * NC;       // 400
  float* out_edge  = out + NB * NC + NB;  // 400*512

  k_embed<<<MPAD, 256, 0, stream>>>(logits, obj_embed_w, pos_input, w_pos1, b_pos1,
                                    bn_gamma, bn_beta, bn_mean, bn_var, w_pos2, b_pos2,
                                    tail1, hist);
  k_g1ov<<<NGB + NC, 256, 0, stream>>>(x, tail1, w_lin, part, boxes, ov_bits);
  k_dists<<<NB, 256, 0, stream>>>(part, b_lin, w_out, b_out, out_dists, ukeys, hist);
  k_sps<<<1, 1024, 0, stream>>>(hist, bases, cursor);
  k_scatter<<<236, 256, 0, stream>>>(ukeys, cursor, gkeys);
  k_binsort<<<256, 256, 0, stream>>>(bases, gkeys);
  k_nms_g2a<<<NGB + 1, 256, 0, stream>>>(ov_bits, gkeys, labels, out_preds,
                                         x, tail1, w_fc, part);
  k_final<<<dim3(8, 13), 256, 0, stream>>>(obj_embed2_w, labels, w_fc, part,
                                           b_fc, out_edge);
}

// Round 9
// 778.381 us; speedup vs baseline: 2.8491x; 2.8491x over previous
//
#include <hip/hip_runtime.h>
#include <hip/hip_bf16.h>
#include <stdint.h>

#define NB 400
#define NC 151
#define DX 4096
#define DE 200
#define DP 128
#define DH 512
#define KREP 4424   // 4096 + 200 + 128
#define TAILW 328   // DE + DP
#define MPAD 416    // 13*32 rows, padded
#define SPLITK 8
#define TILES1 139  // ceil(4424/32) - GEMM1 full K
#define TILES2 132  // 4224/32     - GEMM2a label-independent K
#define NGB 832     // gemm blocks per phase: 8 n * 13 m * 8 z
#define SKSTRIDE 152

__device__ __forceinline__ uint32_t f2ord(float f) {
  uint32_t u = __float_as_uint(f);
  return (u & 0x80000000u) ? ~u : (u | 0x80000000u);
}

// ---------------------------------------------------------------------------
// k_embed: softmax(logits) @ obj_embed_w and pos path -> packed tail1 =
// [obj_embed(200) | pos_embed(128)]. Rows 400..415 zero (pad for float4).
// ---------------------------------------------------------------------------
__global__ __launch_bounds__(256) void k_embed(
    const float* __restrict__ logits, const float* __restrict__ obj_embed_w,
    const float* __restrict__ pos_input, const float* __restrict__ w_pos1,
    const float* __restrict__ b_pos1, const float* __restrict__ bn_gamma,
    const float* __restrict__ bn_beta, const float* __restrict__ bn_mean,
    const float* __restrict__ bn_var, const float* __restrict__ w_pos2,
    const float* __restrict__ b_pos2, float* __restrict__ tail1) {
  int r = blockIdx.x, t = threadIdx.x;
  if (r >= NB) {
    if (t < TAILW) tail1[r * TAILW + t] = 0.f;
    return;
  }
  __shared__ float p[NC];
  __shared__ float red[256];
  __shared__ float hb[32];

  float v = (t < NC) ? logits[r * NC + t] : -INFINITY;
  red[t] = v; __syncthreads();
  for (int s = 128; s > 0; s >>= 1) { if (t < s) red[t] = fmaxf(red[t], red[t + s]); __syncthreads(); }
  float m = red[0]; __syncthreads();
  float e = (t < NC) ? expf(v - m) : 0.f;
  red[t] = e; __syncthreads();
  for (int s = 128; s > 0; s >>= 1) { if (t < s) red[t] += red[t + s]; __syncthreads(); }
  float sum = red[0];
  if (t < NC) p[t] = e / sum;

  if (t < 32) {
    float acc = b_pos1[t];
    for (int k = 0; k < 9; k++) acc += pos_input[r * 9 + k] * w_pos1[k * 32 + t];
    acc = (acc - bn_mean[t]) / sqrtf(bn_var[t] + 1e-5f) * bn_gamma[t] + bn_beta[t];
    hb[t] = acc;
  }
  __syncthreads();

  if (t < DE) {
    float acc = 0.f;
    for (int k = 0; k < NC; k++) acc += p[k] * obj_embed_w[k * DE + t];
    tail1[r * TAILW + t] = acc;
  }
  if (t < DP) {
    float acc = b_pos2[t];
    for (int k = 0; k < 32; k++) acc += hb[k] * w_pos2[k * DP + t];
    tail1[r * TAILW + DE + t] = fmaxf(acc, 0.f);
  }
}

// ---------------------------------------------------------------------------
// gemm_body: split-K partial GEMM tile, 32(M)x64(N), BK=32, 2x4 microtile,
// register prefetch. toff: 0 = full tail1; DE = pos segment (GEMM2a).
// ---------------------------------------------------------------------------
__device__ __forceinline__ void gemm_body(
    const float* __restrict__ x, const float* __restrict__ tail,
    const float* __restrict__ w, float* __restrict__ part,
    int bid, int tiles, int toff, float* As, float* Bs) {
  int tid = threadIdx.x;
  int n0 = (bid & 7) * 64, m0 = ((bid >> 3) % 13) * 32;
  int z = bid / 104;
  int tbeg = (z * tiles) / SPLITK, tend = ((z + 1) * tiles) / SPLITK;
  int ty = tid >> 4, tx = tid & 15;
  int a_r = tid >> 3, a_c = (tid & 7) << 2;
  int b_r = tid >> 4, b_c = (tid & 15) << 2;
  float4 acc0 = {0, 0, 0, 0}, acc1 = {0, 0, 0, 0};

  auto loadA = [&](int t) -> float4 {
    int k = t * 32 + a_c;
    int row = m0 + a_r;
    float4 v = {0, 0, 0, 0};
    if (k < KREP) {
      if (k < DX) { if (row < NB) v = *(const float4*)&x[(size_t)row * DX + k]; }
      else v = *(const float4*)&tail[row * TAILW + toff + (k - DX)];
    }
    return v;
  };
  auto loadB = [&](int t, int roff) -> float4 {
    int k = t * 32 + b_r + roff;
    float4 v = {0, 0, 0, 0};
    if (k < KREP) v = *(const float4*)&w[(size_t)k * DH + n0 + b_c];
    return v;
  };

  float4 pa = loadA(tbeg), pb0 = loadB(tbeg, 0), pb1 = loadB(tbeg, 16);
  for (int t = tbeg; t < tend; t++) {
    __syncthreads();
    *(float4*)&As[a_r * 36 + a_c] = pa;
    *(float4*)&Bs[b_r * 68 + b_c] = pb0;
    *(float4*)&Bs[(b_r + 16) * 68 + b_c] = pb1;
    __syncthreads();
    if (t + 1 < tend) { pa = loadA(t + 1); pb0 = loadB(t + 1, 0); pb1 = loadB(t + 1, 16); }
#pragma unroll
    for (int k4 = 0; k4 < 8; k4++) {
      float4 a0 = *(float4*)&As[(ty * 2) * 36 + k4 * 4];
      float4 a1 = *(float4*)&As[(ty * 2 + 1) * 36 + k4 * 4];
#pragma unroll
      for (int j = 0; j < 4; j++) {
        float4 bv = *(float4*)&Bs[(k4 * 4 + j) * 68 + tx * 4];
        float av0 = (&a0.x)[j], av1 = (&a1.x)[j];
        acc0.x += av0 * bv.x; acc0.y += av0 * bv.y; acc0.z += av0 * bv.z; acc0.w += av0 * bv.w;
        acc1.x += av1 * bv.x; acc1.y += av1 * bv.y; acc1.z += av1 * bv.z; acc1.w += av1 * bv.w;
      }
    }
  }
  int row0 = m0 + ty * 2, col = n0 + tx * 4;
  float* base = part + (size_t)z * NB * DH;
  if (row0 < NB)     *(float4*)&base[row0 * DH + col] = acc0;
  if (row0 + 1 < NB) *(float4*)&base[(row0 + 1) * DH + col] = acc1;
}

// ---------------------------------------------------------------------------
// k_g1ov: blocks 0..831 = GEMM1 partials; blocks 832..982 = IoU bit matrix.
// ---------------------------------------------------------------------------
__global__ __launch_bounds__(256) void k_g1ov(
    const float* __restrict__ x, const float* __restrict__ tail1,
    const float* __restrict__ w_lin, float* __restrict__ part,
    const float* __restrict__ boxes, uint64_t* __restrict__ ov_bits) {
  __shared__ __align__(16) char pool[13312];
  int bid = blockIdx.x;
  if (bid >= NGB) {
    int c = bid - NGB;
    int t = threadIdx.x;
    float4* bx = (float4*)pool;
    const float4* bp4 = (const float4*)boxes;
    for (int j = t; j < NB; j += 256) bx[j] = bp4[j * NC + c];
    __syncthreads();
    int wave = t >> 6, lane = t & 63;
    for (int b = wave; b < NB; b += 4) {
      float4 A = bx[b];
      float areaA = (A.z - A.x + 1.f) * (A.w - A.y + 1.f);
      for (int chunk = 0; chunk < 7; chunk++) {
        int j = chunk * 64 + lane;
        bool ov = false;
        if (j < NB) {
          float4 B = bx[j];
          float x1 = fmaxf(A.x, B.x), y1 = fmaxf(A.y, B.y);
          float x2 = fminf(A.z, B.z), y2 = fminf(A.w, B.w);
          float iw = fmaxf(x2 - x1 + 1.f, 0.f), ih = fmaxf(y2 - y1 + 1.f, 0.f);
          float inter = iw * ih;
          float areaB = (B.z - B.x + 1.f) * (B.w - B.y + 1.f);
          ov = (inter / (areaA + areaB - inter)) >= 0.5f;
        }
        uint64_t mask = __ballot(ov);
        if (lane == 0) ov_bits[((size_t)(b * NC + c) << 3) + chunk] = mask;
      }
    }
    return;
  }
  gemm_body(x, tail1, w_lin, part, bid, TILES1, 0,
            (float*)pool, (float*)(pool + 4608));
}

// ---------------------------------------------------------------------------
// k_dists: hidden = sum of GEMM1 partials + b_lin (LDS); obj_dists -> d_out;
// softmax; emit per-row SORTED key list (value desc, col asc), cols 1..150:
// skeys[r][rank] = (f2ord(v)<<17) | ((511-r)<<8) | col.
// ---------------------------------------------------------------------------
__global__ __launch_bounds__(256) void k_dists(
    const float* __restrict__ part, const float* __restrict__ b_lin,
    const float* __restrict__ w_out, const float* __restrict__ b_out,
    float* __restrict__ out_dists, uint64_t* __restrict__ skeys) {
  int r = blockIdx.x, t = threadIdx.x;
  __shared__ float h[DH];
  __shared__ float red[256];
  __shared__ float sval[NC];
  float s0 = b_lin[t], s1 = b_lin[t + 256];
#pragma unroll
  for (int z = 0; z < SPLITK; z++) {
    const float* pr = part + ((size_t)z * NB + r) * DH;
    s0 += pr[t]; s1 += pr[t + 256];
  }
  h[t] = s0; h[t + 256] = s1;
  __syncthreads();

  float acc = -INFINITY;
  if (t < NC) {
    acc = b_out[t];
    for (int k = 0; k < DH; k++) acc += h[k] * w_out[k * NC + t];
    out_dists[r * NC + t] = acc;
  }
  red[t] = (t < NC) ? acc : -INFINITY; __syncthreads();
  for (int s = 128; s > 0; s >>= 1) { if (t < s) red[t] = fmaxf(red[t], red[t + s]); __syncthreads(); }
  float mx = red[0]; __syncthreads();
  float e = (t < NC) ? expf(acc - mx) : 0.f;
  red[t] = e; __syncthreads();
  for (int s = 128; s > 0; s >>= 1) { if (t < s) red[t] += red[t + s]; __syncthreads(); }
  float sum = red[0];
  if (t < NC) sval[t] = e / sum;
  __syncthreads();

  if (t >= 1 && t < NC) {
    float v = sval[t];
    int rank = 0;
    for (int c2 = 1; c2 < NC; c2++) {
      float v2 = sval[c2];
      rank += (v2 > v) || (v2 == v && c2 < t);
    }
    skeys[(size_t)r * SKSTRIDE + rank] =
        ((uint64_t)f2ord(v) << 17) | ((uint64_t)(511 - r) << 8) | (uint64_t)t;
  }
}

// ---------------------------------------------------------------------------
// k_nms_g2a: block 0 = greedy NMS, single wave, 400 exact steps. Per-row
// ov-row CACHE in LDS (primed for all initial heads; refreshed on pops) makes
// the common pick's overlap row an LDS hit -> serial chain = argmax butterfly
// + LDS reads only. Global loads only on pops (prefetch) / rare cache miss
// (resurrection / fully-suppressed picks). Blocks 1..832 = GEMM2a partials
// over K in [0,4224), hidden under the serial NMS latency.
// ---------------------------------------------------------------------------
__global__ __launch_bounds__(256) void k_nms_g2a(
    const uint64_t* __restrict__ ov_bits, const uint64_t* __restrict__ skeys,
    int* __restrict__ labels_g, float* __restrict__ out_preds,
    const float* __restrict__ x, const float* __restrict__ tail1,
    const float* __restrict__ w_fc, float* __restrict__ part) {
  __shared__ __align__(16) char pool[34816];
  if (blockIdx.x > 0) {
    gemm_body(x, tail1, w_fc, part, blockIdx.x - 1, TILES2, DE,
              (float*)pool, (float*)(pool + 4608));
    return;
  }
  uint64_t* ovc   = (uint64_t*)pool;              // 400*7 u64 = 22400 B
  uint64_t* suppL = (uint64_t*)(pool + 22400);    // 448*3 u64 = 10752 B
  int*      ccol  = (int*)(pool + 33152);         // 400*4 = 1600 B

  int tid = threadIdx.x;
  for (int i = tid; i < 448 * 3; i += 256) suppL[i] = 0;
  for (int r = tid; r < NB; r += 256) {
    labels_g[r] = 0; out_preds[r] = 0.f;
    int hc = (int)(skeys[(size_t)r * SKSTRIDE] & 0xFF);
    ccol[r] = hc;
    const uint64_t* src = ov_bits + (((size_t)(r * NC + hc)) << 3);
#pragma unroll
    for (int k = 0; k < 7; k++) ovc[r * 7 + k] = src[k];
  }
  __syncthreads();
  if (tid >= 64) return;
  int lane = tid;

  const uint64_t SENT = ((uint64_t)0x407FFFFFu << 17);  // f2ord(-1.0) value
  const uint64_t RESV = ((uint64_t)0x80000000u << 17);  // f2ord(0.0) value

  uint64_t cand[7];
  int depth[7], rmin[7];
  uint32_t remm = 0;   // bit s: row s*64+lane removed
#pragma unroll
  for (int s = 0; s < 7; s++) {
    int r = s * 64 + lane;
    cand[s] = (r < NB) ? skeys[(size_t)r * SKSTRIDE] : 0;
    depth[s] = 0; rmin[s] = 255;
  }

  for (int step = 0; step < NB; step++) {
    // global argmax: local max over 7 slots + 6-round butterfly
    uint64_t best = cand[0];
#pragma unroll
    for (int s = 1; s < 7; s++) if (cand[s] > best) best = cand[s];
#pragma unroll
    for (int off = 1; off < 64; off <<= 1) {
      uint64_t o = (uint64_t)__shfl_xor((unsigned long long)best, off, 64);
      if (o > best) best = o;
    }
    int b = 511 - (int)((best >> 8) & 0x1FF);
    int c = (int)(best & 0xFF);

    // overlap row: LDS cache hit (common) or direct fetch (rare)
    uint64_t ow[7];
    if (ccol[b] == c) {
#pragma unroll
      for (int k = 0; k < 7; k++) ow[k] = ovc[b * 7 + k];
    } else {
      uint64_t wv = 0;
      if (lane < 7) wv = ov_bits[(((size_t)(b * NC + c)) << 3) + lane];
#pragma unroll
      for (int k = 0; k < 7; k++) ow[k] = (uint64_t)__shfl((unsigned long long)wv, k, 64);
    }

    // apply pick (b,c)
#pragma unroll
    for (int s = 0; s < 7; s++) {
      int r = s * 64 + lane;
      if (r >= NB) continue;
      if (r == b) {
        remm |= (1u << s); rmin[s] = 255;
        cand[s] = SENT | ((uint64_t)(511 - r) << 8);
        labels_g[b] = c; out_preds[b] = (float)c;
      } else if ((ow[s] >> lane) & 1) {
        if ((remm >> s) & 1) {
          if (c < rmin[s]) rmin[s] = c;   // resurrection: 0.0 at min col
          cand[s] = RESV | ((uint64_t)(511 - r) << 8) | (uint64_t)rmin[s];
        } else {
          suppL[r * 3 + (c >> 6)] |= (1ull << (c & 63));
          if ((int)(cand[s] & 0xFF) == c &&
              (uint32_t)(cand[s] >> 17) > 0x80000000u) {
            // suppressed entry was this row's (positive) head -> pop list
            int d = depth[s] + 1;
            uint64_t nk = 0;
            for (; d < 150; d++) {
              nk = skeys[(size_t)r * SKSTRIDE + d];
              int col = (int)(nk & 0xFF);
              if (!((suppL[r * 3 + (col >> 6)] >> (col & 63)) & 1)) break;
            }
            depth[s] = d;
            if (d >= 150) {   // all cols 1..150 suppressed -> (0.0, col 1)
              cand[s] = RESV | ((uint64_t)(511 - r) << 8) | 1ull;
            } else {
              cand[s] = nk;
              // refresh this row's cache for its new head (off critical path)
              int ncol = (int)(nk & 0xFF);
              const uint64_t* src = ov_bits + (((size_t)(r * NC + ncol)) << 3);
              uint64_t t0 = src[0], t1 = src[1], t2 = src[2], t3 = src[3],
                       t4 = src[4], t5 = src[5], t6 = src[6];
              ovc[r * 7 + 0] = t0; ovc[r * 7 + 1] = t1; ovc[r * 7 + 2] = t2;
              ovc[r * 7 + 3] = t3; ovc[r * 7 + 4] = t4; ovc[r * 7 + 5] = t5;
              ovc[r * 7 + 6] = t6;
              ccol[r] = ncol;
            }
          }
        }
      }
    }
  }
}

// ---------------------------------------------------------------------------
// k_final: edge_ctx = relu( GEMM2a-partials + emb2[labels] @ w_fc[4224:] + b_fc )
// ---------------------------------------------------------------------------
__global__ __launch_bounds__(256) void k_final(
    const float* __restrict__ emb2, const int* __restrict__ labels,
    const float* __restrict__ w_fc, const float* __restrict__ part,
    const float* __restrict__ b_fc, float* __restrict__ out_edge) {
  __shared__ __align__(16) float As[32][36];
  __shared__ __align__(16) float Bs[32][68];
  int tid = threadIdx.x;
  int n0 = blockIdx.x * 64, m0 = blockIdx.y * 32;
  int ty = tid >> 4, tx = tid & 15;
  int a_r = tid >> 3, a_c = (tid & 7) << 2;
  int b_r = tid >> 4, b_c = (tid & 15) << 2;
  float4 acc0 = {0, 0, 0, 0}, acc1 = {0, 0, 0, 0};
  int row_a = m0 + a_r;
  int lab = (row_a < NB) ? labels[row_a] : 0;

  auto loadA = [&](int t) -> float4 {
    int kk = t * 32 + a_c;
    float4 v = {0, 0, 0, 0};
    if (kk < DE && row_a < NB) v = *(const float4*)&emb2[(size_t)lab * DE + kk];
    return v;
  };
  auto loadB = [&](int t, int roff) -> float4 {
    int kk = t * 32 + b_r + roff;
    float4 v = {0, 0, 0, 0};
    if (kk < DE) v = *(const float4*)&w_fc[(size_t)(DX + DP + kk) * DH + n0 + b_c];
    return v;
  };

  float4 pa = loadA(0), pb0 = loadB(0, 0), pb1 = loadB(0, 16);
  for (int t = 0; t < 7; t++) {
    __syncthreads();
    *(float4*)&As[a_r][a_c] = pa;
    *(float4*)&Bs[b_r][b_c] = pb0;
    *(float4*)&Bs[b_r + 16][b_c] = pb1;
    __syncthreads();
    if (t + 1 < 7) { pa = loadA(t + 1); pb0 = loadB(t + 1, 0); pb1 = loadB(t + 1, 16); }
#pragma unroll
    for (int k4 = 0; k4 < 8; k4++) {
      float4 a0 = *(float4*)&As[ty * 2][k4 * 4];
      float4 a1 = *(float4*)&As[ty * 2 + 1][k4 * 4];
#pragma unroll
      for (int j = 0; j < 4; j++) {
        float4 bv = *(float4*)&Bs[k4 * 4 + j][tx * 4];
        float av0 = (&a0.x)[j], av1 = (&a1.x)[j];
        acc0.x += av0 * bv.x; acc0.y += av0 * bv.y; acc0.z += av0 * bv.z; acc0.w += av0 * bv.w;
        acc1.x += av1 * bv.x; acc1.y += av1 * bv.y; acc1.z += av1 * bv.z; acc1.w += av1 * bv.w;
      }
    }
  }
  int row0 = m0 + ty * 2, col = n0 + tx * 4;
#pragma unroll
  for (int z = 0; z < SPLITK; z++) {
    if (row0 < NB) {
      float4 p = *(const float4*)&part[((size_t)z * NB + row0) * DH + col];
      acc0.x += p.x; acc0.y += p.y; acc0.z += p.z; acc0.w += p.w;
    }
    if (row0 + 1 < NB) {
      float4 p = *(const float4*)&part[((size_t)z * NB + row0 + 1) * DH + col];
      acc1.x += p.x; acc1.y += p.y; acc1.z += p.z; acc1.w += p.w;
    }
  }
  float4 bv = *(const float4*)&b_fc[col];
  if (row0 < NB) {
    float4 r;
    r.x = fmaxf(acc0.x + bv.x, 0.f); r.y = fmaxf(acc0.y + bv.y, 0.f);
    r.z = fmaxf(acc0.z + bv.z, 0.f); r.w = fmaxf(acc0.w + bv.w, 0.f);
    *(float4*)&out_edge[row0 * DH + col] = r;
  }
  if (row0 + 1 < NB) {
    float4 r;
    r.x = fmaxf(acc1.x + bv.x, 0.f); r.y = fmaxf(acc1.y + bv.y, 0.f);
    r.z = fmaxf(acc1.z + bv.z, 0.f); r.w = fmaxf(acc1.w + bv.w, 0.f);
    *(float4*)&out_edge[(row0 + 1) * DH + col] = r;
  }
}

// ---------------------------------------------------------------------------
extern "C" void kernel_launch(void* const* d_in, const int* in_sizes, int n_in,
                              void* d_out, int out_size, void* d_ws, size_t ws_size,
                              hipStream_t stream) {
  const float* x            = (const float*)d_in[0];
  const float* logits       = (const float*)d_in[1];
  const float* pos_input    = (const float*)d_in[2];
  const float* boxes        = (const float*)d_in[3];
  const float* obj_embed_w  = (const float*)d_in[4];
  const float* obj_embed2_w = (const float*)d_in[5];
  const float* w_pos1       = (const float*)d_in[6];
  const float* b_pos1       = (const float*)d_in[7];
  const float* bn_gamma     = (const float*)d_in[8];
  const float* bn_beta      = (const float*)d_in[9];
  const float* bn_mean      = (const float*)d_in[10];
  const float* bn_var       = (const float*)d_in[11];
  const float* w_pos2       = (const float*)d_in[12];
  const float* b_pos2       = (const float*)d_in[13];
  const float* w_lin        = (const float*)d_in[14];
  const float* b_lin        = (const float*)d_in[15];
  const float* w_out        = (const float*)d_in[16];
  const float* b_out        = (const float*)d_in[17];
  const float* w_fc         = (const float*)d_in[18];
  const float* b_fc         = (const float*)d_in[19];

  float* ws         = (float*)d_ws;
  float* tail1      = ws;                              // 416*328 floats
  int* labels       = (int*)(tail1 + MPAD * TAILW);    // 512 ints
  uint64_t* skeys   = (uint64_t*)(labels + 512);       // 400*152 u64
  uint64_t* ov_bits = skeys + (size_t)NB * SKSTRIDE;   // 400*151*8 u64
  float* part       = (float*)(ov_bits + (size_t)NB * NC * 8);  // 8*400*512 f

  float* out       = (float*)d_out;
  float* out_dists = out;                 // 400*151
  float* out_preds = out + NB * NC;       // 400
  float* out_edge  = out + NB * NC + NB;  // 400*512

  k_embed<<<MPAD, 256, 0, stream>>>(logits, obj_embed_w, pos_input, w_pos1, b_pos1,
                                    bn_gamma, bn_beta, bn_mean, bn_var, w_pos2, b_pos2,
                                    tail1);
  k_g1ov<<<NGB + NC, 256, 0, stream>>>(x, tail1, w_lin, part, boxes, ov_bits);
  k_dists<<<NB, 256, 0, stream>>>(part, b_lin, w_out, b_out, out_dists, skeys);
  k_nms_g2a<<<NGB + 1, 256, 0, stream>>>(ov_bits, skeys, labels, out_preds,
                                         x, tail1, w_fc, part);
  k_final<<<dim3(8, 13), 256, 0, stream>>>(obj_embed2_w, labels, w_fc, part,
                                           b_fc, out_edge);
}